// Round 12
// baseline (452.735 us; speedup 1.0000x reference)
//
#include <hip/hip_runtime.h>
#include <hip/hip_bf16.h>
#include <math.h>

// B=16, N=1024, C=768, H=12, HD=64, num_mini_batch=1 (m=1024)
// out = proj( TTT_scan( qkv(x) ) )
// R1: bf16 MFMA GEMMs (128x128 tile, BK=32, global_load_lds w=16)  -> 854us, ttt=606us
// R5: ttt split init/grad/apply, 8 chunks/(b,h), atomicAdd merge    -> 479.6us, grad=150us
// R8: MFMA-ize ttt inner matmuls                                    -> 425us, grad=119us
//     BUT: xkr/xvr/etr[16] register arrays spilled to scratch (WRITE_SIZE 25->99MB,
//     VGPR=76 can't hold 48+ floats). Latency-bound on scratch round-trips.
// R9: remove per-row register arrays; read xk/xv/eta (and xq) inline in LN loop
//     (R5's proven pattern). Vectorize Z1^T LDS store as short4v.
// R10/R11: identical resubmission (R9 never ran — GPU acquisition timeouts)

#define Bdim 16
#define Ndim 1024
#define Cdim 768
#define Hdim 12
#define HDdim 64
#define NCH 8          // token chunks per (b,h)
#define CH 128         // tokens per chunk
#define LSTR 72        // LDS row stride in bf16 elems (144B, 16B-aligned rows)

typedef __hip_bfloat16 bf16;
typedef short short8 __attribute__((ext_vector_type(8)));   // 8 bf16 (4 VGPRs)
typedef short short4v __attribute__((ext_vector_type(4)));
typedef float f32x4 __attribute__((ext_vector_type(4)));

__device__ __forceinline__ float wred(float v) {
    #pragma unroll
    for (int o = 32; o > 0; o >>= 1) v += __shfl_xor(v, o);
    return v;
}

__device__ __forceinline__ unsigned short f2bf(float f) {
    __hip_bfloat16 h = __float2bfloat16(f);
    return *reinterpret_cast<unsigned short*>(&h);
}

__device__ __forceinline__ float bf2f(unsigned short u) {
    unsigned int x = ((unsigned int)u) << 16;
    return __uint_as_float(x);
}

__device__ __forceinline__ void gload_lds16(const bf16* g, bf16* l) {
    __builtin_amdgcn_global_load_lds(
        (const __attribute__((address_space(1))) void*)g,
        (__attribute__((address_space(3))) void*)l, 16, 0, 0);
}

// ---------------- cast fp32 -> bf16 (4 elems/thread) ----------------
__global__ __launch_bounds__(256) void cast_kernel(
    const float* __restrict__ in, unsigned short* __restrict__ out)
{
    int i = blockIdx.x * 256 + threadIdx.x;
    float4 v = ((const float4*)in)[i];
    short4v o;
    o.x = f2bf(v.x); o.y = f2bf(v.y); o.z = f2bf(v.z); o.w = f2bf(v.w);
    ((short4v*)out)[i] = o;
}

// ---------------- MFMA GEMM: C[M,N] = A[M,K] @ B[N,K]^T + bias ----------------
template<int BIAS_MODE>
__global__ __launch_bounds__(256) void gemm_bt_mfma(
    const bf16* __restrict__ A, const bf16* __restrict__ B,
    const float* __restrict__ b0, const float* __restrict__ b1v,
    float* __restrict__ C, int M, int N, int K)
{
    __shared__ bf16 As[128 * 32];
    __shared__ bf16 Bs[128 * 32];
    const int tid = threadIdx.x;
    const int wid = tid >> 6, lane = tid & 63;
    const int row0 = blockIdx.x * 128, col0 = blockIdx.y * 128;

    const int srow = lane >> 2;
    const int scol = (lane & 3) * 8;
    const bf16* Ag[2]; const bf16* Bg[2];
    bf16* Al[2]; bf16* Bl[2];
    #pragma unroll
    for (int j = 0; j < 2; ++j) {
        int chunk = wid * 2 + j;
        int r = chunk * 16 + srow;
        Ag[j] = A + (size_t)(row0 + r) * K + scol;
        Bg[j] = B + (size_t)(col0 + r) * K + scol;
        Al[j] = &As[chunk * 16 * 32];
        Bl[j] = &Bs[chunk * 16 * 32];
    }

    const int wm = (wid >> 1) * 64, wn = (wid & 1) * 64;
    const int fr = lane & 15;
    const int fq = lane >> 4;
    f32x4 acc[4][4] = {};

    for (int k0 = 0; k0 < K; k0 += 32) {
        __syncthreads();
        #pragma unroll
        for (int j = 0; j < 2; ++j) {
            gload_lds16(Ag[j] + k0, Al[j]);
            gload_lds16(Bg[j] + k0, Bl[j]);
        }
        __syncthreads();
        short8 af[4], bfr[4];
        #pragma unroll
        for (int i = 0; i < 4; ++i) {
            af[i]  = *(const short8*)&As[(wm + i * 16 + fr) * 32 + fq * 8];
            bfr[i] = *(const short8*)&Bs[(wn + i * 16 + fr) * 32 + fq * 8];
        }
        #pragma unroll
        for (int mi = 0; mi < 4; ++mi)
            #pragma unroll
            for (int ni = 0; ni < 4; ++ni)
                acc[mi][ni] = __builtin_amdgcn_mfma_f32_16x16x32_bf16(
                    af[mi], bfr[ni], acc[mi][ni], 0, 0, 0);
    }

    #pragma unroll
    for (int ni = 0; ni < 4; ++ni) {
        int ccol = col0 + wn + ni * 16 + fr;
        float bias;
        if (BIAS_MODE == 0) bias = (ccol < 768) ? b0[ccol] : (ccol < 1536 ? 0.f : b1v[ccol - 1536]);
        else                bias = b0[ccol];
        #pragma unroll
        for (int mi = 0; mi < 4; ++mi) {
            #pragma unroll
            for (int r = 0; r < 4; ++r) {
                int crow = row0 + wm + mi * 16 + fq * 4 + r;
                C[(size_t)crow * N + ccol] = acc[mi][ni][r] + bias;
            }
        }
    }
}

// ---------------- eta: sigmoid(x . lrw_h + lrb_h)/64, [B,H,N] ----------------
__global__ __launch_bounds__(256) void eta_kernel(
    const float* __restrict__ x, const float* __restrict__ lrw,
    const float* __restrict__ lrb, float* __restrict__ eta)
{
    __shared__ float xs[768];
    const int bn = blockIdx.x;
    const int tid = threadIdx.x, lane = tid & 63, w = tid >> 6;
    const float* xrow = x + (size_t)bn * Cdim;
    if (tid < 192) *(float4*)&xs[tid*4] = *(const float4*)&xrow[tid*4];
    __syncthreads();
    const int b = bn >> 10, n = bn & 1023;
    for (int h = w; h < Hdim; h += 4) {
        float p = 0.f;
        const float* wr = lrw + h * Cdim;
        #pragma unroll
        for (int j = 0; j < 12; ++j) p += xs[lane + j*64] * wr[lane + j*64];
        p = wred(p);
        if (lane == 0) {
            float v = p + lrb[h];
            eta[((size_t)b*Hdim + h)*Ndim + n] = (1.f / (1.f + expf(-v))) * 0.015625f;
        }
    }
}

// ---------------- ttt_init: W1n = W1 (broadcast), bn1 = b1 ----------------
__global__ __launch_bounds__(256) void ttt_init(
    const float* __restrict__ W1g, const float* __restrict__ b1g,
    float* __restrict__ W1n, float* __restrict__ bn1)
{
    const int bh = blockIdx.x, h = bh % Hdim, tid = threadIdx.x;
    #pragma unroll
    for (int j = 0; j < 16; ++j)
        W1n[(size_t)bh * 4096 + j * 256 + tid] = W1g[h * 4096 + j * 256 + tid];
    if (tid < 64) bn1[bh * 64 + tid] = b1g[h * 64 + tid];
}

// ---------------- ttt_grad (MFMA): per (b,h,chunk) accumulate -grad ----------------
// Z1^T[e][t] = mfma(W1T, XK);  LN rows fp32 (inline global reads);
// gradW1^T[e][d] = mfma(G^T, XK^T)
__global__ __launch_bounds__(256) void ttt_grad(
    const float* __restrict__ qkv,    // [B*N, 2304], col = which*768 + h*64 + d
    const float* __restrict__ eta,    // [B,H,N]
    const float* __restrict__ W1g,    // [H,64,64]  (d-major: W1[d][e])
    const float* __restrict__ b1g,
    const float* __restrict__ gammag, const float* __restrict__ betag,
    float* __restrict__ W1n,          // [B*H,64,64] pre-init W1
    float* __restrict__ bn1)          // [B*H,64]    pre-init b1
{
    const int bh = blockIdx.x;
    const int b = bh / Hdim, h = bh % Hdim;
    const int c0base = blockIdx.y * CH;
    const int tid = threadIdx.x, lane = tid & 63, w = tid >> 6;
    const int fr = lane & 15, fq = lane >> 4;

    __shared__ __align__(16) unsigned short XKs [64 * LSTR];  // [t][d]
    __shared__ __align__(16) unsigned short XKTs[64 * LSTR];  // [d][t]
    __shared__ __align__(16) unsigned short W1Ts[64 * LSTR];  // [e][d]
    __shared__ __align__(16) unsigned short Gst [64 * LSTR];  // [e][t]
    __shared__ __align__(16) unsigned short Z1s [64 * LSTR];  // [t][e] (bf16 Z1)
    __shared__ float b1s[64], gms[64], bts[64];
    __shared__ float gb1p[4][64];

    // stage W1^T (once): W1Ts[e][d] = W1[d][e]
    for (int i = tid; i < 4096; i += 256) {
        int d = i >> 6, e = i & 63;
        W1Ts[e * LSTR + d] = f2bf(W1g[h * 4096 + i]);
    }
    if (tid < 64) {
        b1s[tid] = b1g[h*64 + tid];
        gms[tid] = gammag[h*64 + tid];
        bts[tid] = betag[h*64 + tid];
    }
    f32x4 gacc[4] = {};
    float gb1 = 0.f;

    const float* qkv_b = qkv + (size_t)b * Ndim * 2304 + h * 64;
    const float* eta_b = eta + ((size_t)b * Hdim + h) * Ndim;
    __syncthreads();

    #pragma unroll 1
    for (int half = 0; half < 2; ++half) {
        const int c0 = c0base + half * 64;
        // ---- stage XK (natural + transposed), bf16 ----
        #pragma unroll
        for (int j = 0; j < 4; ++j) {
            int f = tid + j * 256;
            int r = f >> 4, c4 = (f & 15) << 2;
            float4 v = *(const float4*)(qkv_b + (size_t)(c0 + r)*2304 + 768 + c4);
            unsigned short u0 = f2bf(v.x), u1 = f2bf(v.y), u2 = f2bf(v.z), u3 = f2bf(v.w);
            short4v sv; sv.x = (short)u0; sv.y = (short)u1; sv.z = (short)u2; sv.w = (short)u3;
            *(short4v*)&XKs[r * LSTR + c4] = sv;
            XKTs[(c4+0) * LSTR + r] = u0;
            XKTs[(c4+1) * LSTR + r] = u1;
            XKTs[(c4+2) * LSTR + r] = u2;
            XKTs[(c4+3) * LSTR + r] = u3;
        }
        __syncthreads();
        // ---- Z1^T[e][t] = sum_d W1T[e][d] * XK[t][d]; wave w: e-strip w*16 ----
        {
            short8 a0 = *(const short8*)&W1Ts[(w*16 + fr) * LSTR + 0  + fq*8];
            short8 a1 = *(const short8*)&W1Ts[(w*16 + fr) * LSTR + 32 + fq*8];
            f32x4 zacc[4] = {};
            #pragma unroll
            for (int nt = 0; nt < 4; ++nt) {
                short8 b0 = *(const short8*)&XKs[(nt*16 + fr) * LSTR + 0  + fq*8];
                short8 b1_ = *(const short8*)&XKs[(nt*16 + fr) * LSTR + 32 + fq*8];
                zacc[nt] = __builtin_amdgcn_mfma_f32_16x16x32_bf16(a0, b0, zacc[nt], 0, 0, 0);
                zacc[nt] = __builtin_amdgcn_mfma_f32_16x16x32_bf16(a1, b1_, zacc[nt], 0, 0, 0);
            }
            // store Z1s[t][e]: t = nt*16 + fr (B-frag index), e = w*16 + fq*4 + rr
            #pragma unroll
            for (int nt = 0; nt < 4; ++nt) {
                short4v zs;
                zs.x = (short)f2bf(zacc[nt][0]);
                zs.y = (short)f2bf(zacc[nt][1]);
                zs.z = (short)f2bf(zacc[nt][2]);
                zs.w = (short)f2bf(zacc[nt][3]);
                *(short4v*)&Z1s[(nt*16 + fr) * LSTR + (w*16 + fq*4)] = zs;
            }
        }
        __syncthreads();
        // ---- LN rows (fp32), wave w: rows [w*16, w*16+16); inline global reads ----
        #pragma unroll 1
        for (int i = 0; i < 16; ++i) {
            int r = w*16 + i;
            int n = c0 + r;
            float xk = qkv_b[(size_t)n * 2304 + 768 + lane];
            float xv = qkv_b[(size_t)n * 2304 + 1536 + lane];
            float etav = eta_b[n];
            float z = bf2f(Z1s[r * LSTR + lane]) + b1s[lane];
            float mu = wred(z) * 0.015625f;
            float zc = z - mu;
            float var = wred(zc * zc) * 0.015625f;
            float rstd = rsqrtf(var + 1e-6f);
            float xh = zc * rstd;
            float gm = gms[lane];
            float gg = (gm * xh + bts[lane] - (xv - xk)) * gm;
            float s1 = wred(gg);
            float s2 = wred(gg * xh);
            float gf = (64.f * gg - s1 - xh * s2) * rstd * 0.015625f * etav * 0.0009765625f;
            gb1 += gf;
            Gst[lane * LSTR + r] = f2bf(gf);
        }
        __syncthreads();
        // ---- gradW1^T[e][d] += sum_t G[t][e] * XK[t][d]; wave w: e-strip ----
        {
            short8 a0 = *(const short8*)&Gst[(w*16 + fr) * LSTR + 0  + fq*8];
            short8 a1 = *(const short8*)&Gst[(w*16 + fr) * LSTR + 32 + fq*8];
            #pragma unroll
            for (int nt = 0; nt < 4; ++nt) {
                short8 b0 = *(const short8*)&XKTs[(nt*16 + fr) * LSTR + 0  + fq*8];
                short8 b1_ = *(const short8*)&XKTs[(nt*16 + fr) * LSTR + 32 + fq*8];
                gacc[nt] = __builtin_amdgcn_mfma_f32_16x16x32_bf16(a0, b0, gacc[nt], 0, 0, 0);
                gacc[nt] = __builtin_amdgcn_mfma_f32_16x16x32_bf16(a1, b1_, gacc[nt], 0, 0, 0);
            }
        }
        __syncthreads();   // protect restage of XKs/XKTs/Gst/Z1s
    }

    // ---- finalize: atomic -grad into W1n (elem grad_W1[d][e] = D[e][d]) ----
    #pragma unroll
    for (int nt = 0; nt < 4; ++nt) {
        int d = nt*16 + fr;
        #pragma unroll
        for (int rr = 0; rr < 4; ++rr) {
            int e = w*16 + fq*4 + rr;
            atomicAdd(&W1n[(size_t)bh * 4096 + d * 64 + e], -gacc[nt][rr]);
        }
    }
    gb1p[w][lane] = gb1;
    __syncthreads();
    if (tid < 64) {
        float s = gb1p[0][tid] + gb1p[1][tid] + gb1p[2][tid] + gb1p[3][tid];
        atomicAdd(&bn1[bh * 64 + tid], -s);
    }
}

// ---------------- ttt_apply (MFMA): inner = XQ + LN(XQ@W1n + bn1) ----------------
__global__ __launch_bounds__(256) void ttt_apply(
    const float* __restrict__ qkv,
    const float* __restrict__ W1n, const float* __restrict__ bn1,
    const float* __restrict__ gammag, const float* __restrict__ betag,
    unsigned short* __restrict__ inner)   // bf16 [B*N, 768]
{
    const int bh = blockIdx.x;
    const int b = bh / Hdim, h = bh % Hdim;
    const int c0base = blockIdx.y * CH;
    const int tid = threadIdx.x, lane = tid & 63, w = tid >> 6;
    const int fr = lane & 15, fq = lane >> 4;

    __shared__ __align__(16) unsigned short XQs  [64 * LSTR];  // [t][d]
    __shared__ __align__(16) unsigned short W1nTs[64 * LSTR];  // [e][d]
    __shared__ __align__(16) unsigned short Z1s  [64 * LSTR];  // [t][e]
    __shared__ float bn1s[64], gms[64], bts[64];

    for (int i = tid; i < 4096; i += 256) {
        int d = i >> 6, e = i & 63;
        W1nTs[e * LSTR + d] = f2bf(W1n[(size_t)bh * 4096 + i]);
    }
    if (tid < 64) {
        bn1s[tid] = bn1[bh*64 + tid];
        gms[tid] = gammag[h*64 + tid];
        bts[tid] = betag[h*64 + tid];
    }
    const float* qkv_b = qkv + (size_t)b * Ndim * 2304 + h * 64;
    __syncthreads();

    #pragma unroll 1
    for (int half = 0; half < 2; ++half) {
        const int c0 = c0base + half * 64;
        // ---- stage XQ bf16 ----
        #pragma unroll
        for (int j = 0; j < 4; ++j) {
            int f = tid + j * 256;
            int r = f >> 4, c4 = (f & 15) << 2;
            float4 v = *(const float4*)(qkv_b + (size_t)(c0 + r)*2304 + 0 + c4);
            short4v sv; sv.x = (short)f2bf(v.x); sv.y = (short)f2bf(v.y);
            sv.z = (short)f2bf(v.z); sv.w = (short)f2bf(v.w);
            *(short4v*)&XQs[r * LSTR + c4] = sv;
        }
        __syncthreads();
        // ---- Z^T[e][t] = sum_d W1nT[e][d] * XQ[t][d] ----
        {
            short8 a0 = *(const short8*)&W1nTs[(w*16 + fr) * LSTR + 0  + fq*8];
            short8 a1 = *(const short8*)&W1nTs[(w*16 + fr) * LSTR + 32 + fq*8];
            f32x4 zacc[4] = {};
            #pragma unroll
            for (int nt = 0; nt < 4; ++nt) {
                short8 b0 = *(const short8*)&XQs[(nt*16 + fr) * LSTR + 0  + fq*8];
                short8 b1_ = *(const short8*)&XQs[(nt*16 + fr) * LSTR + 32 + fq*8];
                zacc[nt] = __builtin_amdgcn_mfma_f32_16x16x32_bf16(a0, b0, zacc[nt], 0, 0, 0);
                zacc[nt] = __builtin_amdgcn_mfma_f32_16x16x32_bf16(a1, b1_, zacc[nt], 0, 0, 0);
            }
            #pragma unroll
            for (int nt = 0; nt < 4; ++nt) {
                short4v zs;
                zs.x = (short)f2bf(zacc[nt][0]);
                zs.y = (short)f2bf(zacc[nt][1]);
                zs.z = (short)f2bf(zacc[nt][2]);
                zs.w = (short)f2bf(zacc[nt][3]);
                *(short4v*)&Z1s[(nt*16 + fr) * LSTR + (w*16 + fq*4)] = zs;
            }
        }
        __syncthreads();
        // ---- LN rows fp32, wave strip; inline xq read; out = xq + gamma*xh + beta ----
        #pragma unroll 1
        for (int i = 0; i < 16; ++i) {
            int r = w*16 + i;
            int n = c0 + r;
            float xq = qkv_b[(size_t)n * 2304 + 0 + lane];
            float z = bf2f(Z1s[r * LSTR + lane]) + bn1s[lane];
            float mu = wred(z) * 0.015625f;
            float zc = z - mu;
            float var = wred(zc * zc) * 0.015625f;
            float rstd = rsqrtf(var + 1e-6f);
            float xh = zc * rstd;
            inner[(size_t)(b * Ndim + n) * Cdim + h * 64 + lane] =
                f2bf(xq + gms[lane] * xh + bts[lane]);
        }
        __syncthreads();   // protect restage of XQs/Z1s
    }
}

extern "C" void kernel_launch(void* const* d_in, const int* in_sizes, int n_in,
                              void* d_out, int out_size, void* d_ws, size_t ws_size,
                              hipStream_t stream) {
    const float* x     = (const float*)d_in[0];
    const float* qkvw  = (const float*)d_in[1];
    const float* qb    = (const float*)d_in[2];
    const float* vb    = (const float*)d_in[3];
    const float* pw    = (const float*)d_in[4];
    const float* pb    = (const float*)d_in[5];
    const float* lrw   = (const float*)d_in[6];
    const float* lrb   = (const float*)d_in[7];
    const float* gamma = (const float*)d_in[8];
    const float* beta  = (const float*)d_in[9];
    const float* W1    = (const float*)d_in[10];
    const float* b1    = (const float*)d_in[11];
    float* out = (float*)d_out;

    // workspace layout
    float* qkv = (float*)d_ws;                                  // 16384*2304 f32
    float* eta = qkv + (size_t)16384 * 2304;                    // 196608 f32
    unsigned short* inner = (unsigned short*)(eta + 196608);    // bf16 16384*768
    unsigned short* xb    = inner + (size_t)16384 * 768;        // bf16 x
    unsigned short* qkvwb = xb + (size_t)16384 * 768;           // bf16 qkv_weight
    unsigned short* pwb   = qkvwb + (size_t)2304 * 768;         // bf16 proj_weight
    float* W1n = (float*)(pwb + (size_t)768 * 768);             // [192,64,64] f32
    float* bn1 = W1n + (size_t)192 * 4096;                      // [192,64] f32

    // 0) casts to bf16
    cast_kernel<<<16384 * 768 / 1024, 256, 0, stream>>>(x, xb);
    cast_kernel<<<2304 * 768 / 1024, 256, 0, stream>>>(qkvw, qkvwb);
    cast_kernel<<<768 * 768 / 1024, 256, 0, stream>>>(pw, pwb);

    // 1) qkv = x @ qkv_weight^T + [q_bias, 0, v_bias]
    gemm_bt_mfma<0><<<dim3(16384 / 128, 2304 / 128), 256, 0, stream>>>(
        (const bf16*)xb, (const bf16*)qkvwb, qb, vb, qkv, 16384, 2304, Cdim);

    // 2) eta
    eta_kernel<<<Bdim * Ndim, 256, 0, stream>>>(x, lrw, lrb, eta);

    // 3) ttt: init -> grad (MFMA, sharded, atomic) -> apply (MFMA, sharded)
    ttt_init<<<Bdim * Hdim, 256, 0, stream>>>(W1, b1, W1n, bn1);
    ttt_grad<<<dim3(Bdim * Hdim, NCH), 256, 0, stream>>>(
        qkv, eta, W1, b1, gamma, beta, W1n, bn1);
    ttt_apply<<<dim3(Bdim * Hdim, NCH), 256, 0, stream>>>(
        qkv, W1n, bn1, gamma, beta, inner);

    // 4) out = inner @ proj_weight^T + proj_bias
    gemm_bt_mfma<1><<<dim3(16384 / 128, 768 / 128), 256, 0, stream>>>(
        (const bf16*)inner, (const bf16*)pwb, pb, nullptr, out, 16384, Cdim, Cdim);
}